// Round 3
// baseline (290679.077 us; speedup 1.0000x reference)
//
#include <hip/hip_runtime.h>

#define B_   256
#define T_   512
#define H_   512
#define C_   10
#define NGRP 8      // batch groups (32 batches each)
#define BPG  32
#define JT   16     // j-outputs per block
#define NJT  32     // blocks per batch group
#define NTHR 512    // 8 waves x 4 batches/wave; 2 waves/SIMD TLP
// W' layout: [kc=128][gj=64][kk=4] floats = 128 KiB exactly -> 1 block/CU.
// Wave ds_read_b128 at (kc*1024 + lane*16) is a contiguous 1024 B line: zero
// redundancy, zero bank conflicts (stride-1 b128).
#define LDS_BYTES (4 * JT * H_ * 4)

// numpy-SIMD-style (cephes/avx_mathfun) f32 exp — r9-flagged V2 model. DO NOT TOUCH.
__device__ __forceinline__ float expf_cephes(float x) {
    x = fminf(x, 88.3762626647949f);
    x = fmaxf(x, -88.3762626647949f);
    float fx = __fmaf_rn(x, 1.44269504088896341f, 0.5f);
    fx = floorf(fx);
    x = __fmaf_rn(fx, -0.693359375f, x);
    x = __fmaf_rn(fx, 2.12194440e-4f, x);
    float z = __fmul_rn(x, x);
    float y = 1.9875691500E-4f;
    y = __fmaf_rn(y, x, 1.3981999507E-3f);
    y = __fmaf_rn(y, x, 8.3334519073E-3f);
    y = __fmaf_rn(y, x, 4.1665795894E-2f);
    y = __fmaf_rn(y, x, 1.6666665459E-1f);
    y = __fmaf_rn(y, x, 5.0000001201E-1f);
    y = __fmaf_rn(y, z, x);
    y = __fadd_rn(y, 1.0f);
    return ldexpf(y, (int)fx);
}

__device__ __forceinline__ float sig_np(float pre) {
    float e = expf_cephes(-pre);
    return __fdiv_rn(1.0f, __fadd_rn(1.0f, e));
}

// k-ascending 4-FMA chain segment — identical op/operand order to r2 (passed),
// so every (b,j,gate) accumulator chain is bit-identical.
#define FMA4(acc, h4, w4)                                                       \
    acc = __fmaf_rn((h4).x, (w4).x, acc); acc = __fmaf_rn((h4).y, (w4).y, acc); \
    acc = __fmaf_rn((h4).z, (w4).z, acc); acc = __fmaf_rn((h4).w, (w4).w, acc);

// ---- mega-chunk (16 k) A/B double buffer ---------------------------------
// Per buffer: 4 W float4 (lane-distinct, LDS) + 16 h float4 (wave-uniform
// broadcast, global) = 80 VGPR. Both buffers + acc + addr ~210 VGPR < 256 cap.
// sched_barrier(0) after each load group PINS the loads early — rounds 1/2
// proved the scheduler otherwise sinks them to their uses (VGPR 68/108) and
// the pipeline collapses to ~0 prefetch distance.
#define LOADM(P, q)                                                             \
    W##P##0 = wr[(((q)+0)<<6)+l]; W##P##1 = wr[(((q)+1)<<6)+l];                 \
    W##P##2 = wr[(((q)+2)<<6)+l]; W##P##3 = wr[(((q)+3)<<6)+l];                 \
    H##P##00 = hr0[(q)+0]; H##P##01 = hr0[(q)+1];                               \
    H##P##02 = hr0[(q)+2]; H##P##03 = hr0[(q)+3];                               \
    H##P##10 = hr1[(q)+0]; H##P##11 = hr1[(q)+1];                               \
    H##P##12 = hr1[(q)+2]; H##P##13 = hr1[(q)+3];                               \
    H##P##20 = hr2[(q)+0]; H##P##21 = hr2[(q)+1];                               \
    H##P##22 = hr2[(q)+2]; H##P##23 = hr2[(q)+3];                               \
    H##P##30 = hr3[(q)+0]; H##P##31 = hr3[(q)+1];                               \
    H##P##32 = hr3[(q)+2]; H##P##33 = hr3[(q)+3];                               \
    __builtin_amdgcn_sched_barrier(0);

// 64 FMAs consuming buffer P; k strictly ascending within every chain.
#define COMPM(P)                                                                \
    FMA4(a0, H##P##00, W##P##0) FMA4(a1, H##P##10, W##P##0)                     \
    FMA4(a2, H##P##20, W##P##0) FMA4(a3, H##P##30, W##P##0)                     \
    FMA4(a0, H##P##01, W##P##1) FMA4(a1, H##P##11, W##P##1)                     \
    FMA4(a2, H##P##21, W##P##1) FMA4(a3, H##P##31, W##P##1)                     \
    FMA4(a0, H##P##02, W##P##2) FMA4(a1, H##P##12, W##P##2)                     \
    FMA4(a2, H##P##22, W##P##2) FMA4(a3, H##P##32, W##P##2)                     \
    FMA4(a0, H##P##03, W##P##3) FMA4(a1, H##P##13, W##P##3)                     \
    FMA4(a2, H##P##23, W##P##3) FMA4(a3, H##P##33, W##P##3)

// Epilogue per batch: gather all 4 gate pre-activations to every lane via
// ds_bpermute (pure data movement — values are the bit-exact per-gate chains),
// then V2 rounding verbatim. All 4 gate-groups compute c/h redundantly
// (identical deterministic ops); gate-group g stores batch bi==g.
#define EPI(bi, av, cv)                                                         \
    {                                                                           \
        const float pre = __fadd_rn(__fadd_rn(__fmul_rn(wx, xt##bi), av), bs);  \
        const int pbits = __float_as_int(pre);                                  \
        const float pg = __int_as_float(__builtin_amdgcn_ds_bpermute(ix0, pbits)); \
        const float pi = __int_as_float(__builtin_amdgcn_ds_bpermute(ix1, pbits)); \
        const float pf = __int_as_float(__builtin_amdgcn_ds_bpermute(ix2, pbits)); \
        const float po = __int_as_float(__builtin_amdgcn_ds_bpermute(ix3, pbits)); \
        const float iv = sig_np(pi);                                            \
        const float fv = sig_np(pf);                                            \
        const float ov = sig_np(po);                                            \
        cv = __fadd_rn(__fmul_rn(pg, iv), __fmul_rn(cv, fv));                   \
        const float hn = __fmul_rn(cv, ov);                                     \
        if ((bi) == g) hwp[(bi) * H_] = hn;                                     \
    }

__global__ void __launch_bounds__(NTHR, 1) lstm_fast(
    const float* __restrict__ x,
    const float* __restrict__ wgh, const float* __restrict__ wih,
    const float* __restrict__ wfh, const float* __restrict__ woh,
    const float* __restrict__ wgx, const float* __restrict__ wix,
    const float* __restrict__ wfx, const float* __restrict__ wox,
    const float* __restrict__ bgp, const float* __restrict__ bip,
    const float* __restrict__ bfp, const float* __restrict__ bop,
    float* __restrict__ hbuf, unsigned int* __restrict__ cnt)
{
    extern __shared__ float lds[];   // W'[kc][gj][kk]
    const int tid = threadIdx.x;
    const int bg  = blockIdx.x & (NGRP - 1);
    const int jt  = blockIdx.x >> 3;
    const int j0  = jt * JT;

    // stage: lds[(k>>2)*256 + (g*16+jj)*4 + (k&3)] = W_g[k][j0+jj]  (exact f32 bits)
    const float* wh[4] = {wgh, wih, wfh, woh};
    for (int g2 = 0; g2 < 4; ++g2) {
        const float* w = wh[g2];
        for (int idx = tid; idx < H_ * JT; idx += NTHR) {
            const int k   = idx >> 4;
            const int jj2 = idx & (JT - 1);
            lds[((k >> 2) << 8) + (((g2 << 4) + jj2) << 2) + (k & 3)] =
                w[k * H_ + j0 + jj2];
        }
    }
    __syncthreads();

    // lane mapping: l = (gate g, column jj); wave wv owns 4 batches in registers.
    const int l   = tid & 63;
    const int wv  = tid >> 6;                 // 0..7
    const int g   = l >> 4;
    const int jj  = l & 15;
    const int jg  = j0 + jj;
    const int b0w = bg * BPG + wv * 4;

    const float* wxs = (g == 0) ? wgx : (g == 1) ? wix : (g == 2) ? wfx : wox;
    const float* bss = (g == 0) ? bgp : (g == 1) ? bip : (g == 2) ? bfp : bop;
    const float wx = wxs[jg];
    const float bs = bss[jg];

    // bpermute byte-indices: gate-0..3 lanes holding this jj
    const int ix0 = (jj + 0)  << 2;
    const int ix1 = (jj + 16) << 2;
    const int ix2 = (jj + 32) << 2;
    const int ix3 = (jj + 48) << 2;

    const float4* wr = (const float4*)lds;

    float c0 = 0.f, c1 = 0.f, c2 = 0.f, c3 = 0.f;

    for (int t = 0; t < T_; ++t) {
        if (t > 0) {
            if (tid == 0) {
                while (__hip_atomic_load(&cnt[t * NGRP + bg], __ATOMIC_RELAXED,
                                         __HIP_MEMORY_SCOPE_AGENT) < NJT) {
                    __builtin_amdgcn_s_sleep(1);
                }
                (void)__hip_atomic_load(&cnt[t * NGRP + bg], __ATOMIC_ACQUIRE,
                                        __HIP_MEMORY_SCOPE_AGENT);
            }
            __syncthreads();
        }

        const float xt0 = x[(b0w + 0) * T_ + t];
        const float xt1 = x[(b0w + 1) * T_ + t];
        const float xt2 = x[(b0w + 2) * T_ + t];
        const float xt3 = x[(b0w + 3) * T_ + t];

        const float* hb = hbuf + (size_t)(t & 1) * B_ * H_;
        const float4* hr0 = (const float4*)(hb + (b0w + 0) * H_);
        const float4* hr1 = (const float4*)(hb + (b0w + 1) * H_);
        const float4* hr2 = (const float4*)(hb + (b0w + 2) * H_);
        const float4* hr3 = (const float4*)(hb + (b0w + 3) * H_);

        float a0 = 0.f, a1 = 0.f, a2 = 0.f, a3 = 0.f;

        float4 WA0, WA1, WA2, WA3, WB0, WB1, WB2, WB3;
        float4 HA00, HA01, HA02, HA03, HA10, HA11, HA12, HA13;
        float4 HA20, HA21, HA22, HA23, HA30, HA31, HA32, HA33;
        float4 HB00, HB01, HB02, HB03, HB10, HB11, HB12, HB13;
        float4 HB20, HB21, HB22, HB23, HB30, HB31, HB32, HB33;

        // 32 megas of 16 k; A/B ping-pong, loads pinned early by sched_barrier.
        LOADM(A, 0)
        LOADM(B, 4)
        #pragma unroll
        for (int mm = 0; mm < 15; ++mm) {
            const int q = mm * 8;
            COMPM(A) LOADM(A, q + 8)
            COMPM(B) LOADM(B, q + 12)
        }
        COMPM(A) COMPM(B)   // megas 30, 31 (kc 120..127)

        float* hw  = hbuf + (size_t)((t + 1) & 1) * B_ * H_;
        float* hwp = hw + b0w * H_ + jg;

        EPI(0, a0, c0) EPI(1, a1, c1) EPI(2, a2, c2) EPI(3, a3, c3)

        __syncthreads();   // s_waitcnt vmcnt(0) before s_barrier: h stores drained
        if (tid == 0) {
            // RELEASE fetch_add alone provides the store->flag release fence.
            __hip_atomic_fetch_add(&cnt[(t + 1) * NGRP + bg], 1u,
                                   __ATOMIC_RELEASE, __HIP_MEMORY_SCOPE_AGENT);
        }
    }
}

// out[b][c] = dot_seq(h_T[b], wph[c]) + bp[c]  — bit-identical chain to r12's proj
__global__ void __launch_bounds__(64) proj_kernel(
    const float* __restrict__ hbuf, const float* __restrict__ wph,
    const float* __restrict__ bp, float* __restrict__ out)
{
    const int b = blockIdx.x, tid = threadIdx.x;
    const float* h = hbuf + (size_t)b * H_;   // final h in buffer 0 (T even)
    if (tid < C_) {
        float acc = 0.f;
        for (int k = 0; k < H_; ++k)
            acc = __fmaf_rn(h[k], wph[tid * H_ + k], acc);
        out[b * C_ + tid] = __fadd_rn(acc, bp[tid]);
    }
}

extern "C" void kernel_launch(void* const* d_in, const int* in_sizes, int n_in,
                              void* d_out, int out_size, void* d_ws, size_t ws_size,
                              hipStream_t stream)
{
    const float* x   = (const float*)d_in[0];
    const float* wgx = (const float*)d_in[1];
    const float* wgh = (const float*)d_in[2];
    const float* bgp = (const float*)d_in[3];
    const float* wix = (const float*)d_in[4];
    const float* wih = (const float*)d_in[5];
    const float* bip = (const float*)d_in[6];
    const float* wfx = (const float*)d_in[7];
    const float* wfh = (const float*)d_in[8];
    const float* bfp = (const float*)d_in[9];
    const float* wox = (const float*)d_in[10];
    const float* woh = (const float*)d_in[11];
    const float* bop = (const float*)d_in[12];
    const float* wph = (const float*)d_in[13];
    const float* bp  = (const float*)d_in[14];
    float* out = (float*)d_out;

    float* hbuf = (float*)d_ws;                                   // 2*B*H f32 = 1 MB
    unsigned int* cnt = (unsigned int*)((char*)d_ws + (size_t)2 * B_ * H_ * 4);
    size_t zero_bytes = (size_t)2 * B_ * H_ * 4 + (size_t)(T_ + 1) * NGRP * 4;
    hipMemsetAsync(d_ws, 0, zero_bytes, stream);   // h0 = 0, counters = 0

    hipFuncSetAttribute((const void*)lstm_fast,
                        hipFuncAttributeMaxDynamicSharedMemorySize, LDS_BYTES);

    void* args[] = {&x, &wgh, &wih, &wfh, &woh, &wgx, &wix, &wfx, &wox,
                    &bgp, &bip, &bfp, &bop, &hbuf, &cnt};
    hipLaunchCooperativeKernel((const void*)lstm_fast, dim3(NGRP * NJT), dim3(NTHR),
                               args, LDS_BYTES, stream);

    proj_kernel<<<B_, 64, 0, stream>>>(hbuf, wph, bp, out);
}

// Round 4
// 12883.266 us; speedup vs baseline: 22.5625x; 22.5625x over previous
//
#include <hip/hip_runtime.h>

#define B_   256
#define T_   512
#define H_   512
#define C_   10
#define NGRP 8      // batch groups (32 batches each)
#define BPG  32
#define JT   16     // j-outputs per block
#define NJT  32     // blocks per batch group
#define NTHR 512    // 8 waves x 4 batches/wave; 2 waves/SIMD TLP
#define WF   (4 * JT * H_)   // 32768 floats: W'[kc=128][gj=64][kk=4] = 128 KiB
#define HCH  2048            // floats per h buffer: [32 b][64 k] = 8 KiB
// 128K (W) + 2x8K (h dbuf) = 144 KiB -> 1 block/CU
#define LDS_BYTES ((WF + 2 * HCH) * 4)

// numpy-SIMD-style (cephes/avx_mathfun) f32 exp — r9-flagged V2 model. DO NOT TOUCH.
__device__ __forceinline__ float expf_cephes(float x) {
    x = fminf(x, 88.3762626647949f);
    x = fmaxf(x, -88.3762626647949f);
    float fx = __fmaf_rn(x, 1.44269504088896341f, 0.5f);
    fx = floorf(fx);
    x = __fmaf_rn(fx, -0.693359375f, x);
    x = __fmaf_rn(fx, 2.12194440e-4f, x);
    float z = __fmul_rn(x, x);
    float y = 1.9875691500E-4f;
    y = __fmaf_rn(y, x, 1.3981999507E-3f);
    y = __fmaf_rn(y, x, 8.3334519073E-3f);
    y = __fmaf_rn(y, x, 4.1665795894E-2f);
    y = __fmaf_rn(y, x, 1.6666665459E-1f);
    y = __fmaf_rn(y, x, 5.0000001201E-1f);
    y = __fmaf_rn(y, z, x);
    y = __fadd_rn(y, 1.0f);
    return ldexpf(y, (int)fx);
}

__device__ __forceinline__ float sig_np(float pre) {
    float e = expf_cephes(-pre);
    return __fdiv_rn(1.0f, __fadd_rn(1.0f, e));
}

// Zero-VGPR async global->LDS stage (16 B/lane). In-flight data lives in the
// vmem queue, NOT registers -> nothing for the allocator to sink (r1/r2) or
// spill (r3). LDS dest = wave-uniform base + lane*16 (HW rule).
__device__ __forceinline__ void stage_h16(const float* g, float* l) {
    __builtin_amdgcn_global_load_lds(
        (const __attribute__((address_space(1))) void*)g,
        (__attribute__((address_space(3))) void*)l, 16, 0, 0);
}

// k-ascending 4-FMA chain segment — identical op/operand order to r2 (passed),
// so every (b,j,gate) accumulator chain is bit-identical.
#define FMA4(acc, h4, w4)                                                       \
    acc = __fmaf_rn((h4).x, (w4).x, acc); acc = __fmaf_rn((h4).y, (w4).y, acc); \
    acc = __fmaf_rn((h4).z, (w4).z, acc); acc = __fmaf_rn((h4).w, (w4).w, acc);

// Epilogue per batch: gather all 4 gate pre-activations to every lane via
// ds_bpermute (pure data movement — values are the bit-exact per-gate chains),
// then V2 rounding verbatim. All 4 gate-groups compute c/h redundantly
// (identical deterministic ops); gate-group g stores batch bi==g.
#define EPI(bi, av, cv)                                                         \
    {                                                                           \
        const float pre = __fadd_rn(__fadd_rn(__fmul_rn(wx, xt##bi), av), bs);  \
        const int pbits = __float_as_int(pre);                                  \
        const float pg = __int_as_float(__builtin_amdgcn_ds_bpermute(ix0, pbits)); \
        const float pi = __int_as_float(__builtin_amdgcn_ds_bpermute(ix1, pbits)); \
        const float pf = __int_as_float(__builtin_amdgcn_ds_bpermute(ix2, pbits)); \
        const float po = __int_as_float(__builtin_amdgcn_ds_bpermute(ix3, pbits)); \
        const float iv = sig_np(pi);                                            \
        const float fv = sig_np(pf);                                            \
        const float ov = sig_np(po);                                            \
        cv = __fadd_rn(__fmul_rn(pg, iv), __fmul_rn(cv, fv));                   \
        const float hn = __fmul_rn(cv, ov);                                     \
        if ((bi) == g) hwp[(bi) * H_] = hn;                                     \
    }

__global__ void __launch_bounds__(NTHR, 1) lstm_fast(
    const float* __restrict__ x,
    const float* __restrict__ wgh, const float* __restrict__ wih,
    const float* __restrict__ wfh, const float* __restrict__ woh,
    const float* __restrict__ wgx, const float* __restrict__ wix,
    const float* __restrict__ wfx, const float* __restrict__ wox,
    const float* __restrict__ bgp, const float* __restrict__ bip,
    const float* __restrict__ bfp, const float* __restrict__ bop,
    float* __restrict__ hbuf, unsigned int* __restrict__ cnt)
{
    extern __shared__ float lds[];   // [W' 128K][h buf0 8K][h buf1 8K]
    const int tid = threadIdx.x;
    const int bg  = blockIdx.x & (NGRP - 1);
    const int jt  = blockIdx.x >> 3;
    const int j0  = jt * JT;

    // stage W': lds[(k>>2)*256 + (g*16+jj)*4 + (k&3)] = W_g[k][j0+jj]  (exact bits)
    const float* wh[4] = {wgh, wih, wfh, woh};
    for (int g2 = 0; g2 < 4; ++g2) {
        const float* w = wh[g2];
        for (int idx = tid; idx < H_ * JT; idx += NTHR) {
            const int k   = idx >> 4;
            const int jj2 = idx & (JT - 1);
            lds[((k >> 2) << 8) + (((g2 << 4) + jj2) << 2) + (k & 3)] =
                w[k * H_ + j0 + jj2];
        }
    }
    __syncthreads();

    // lane mapping: l = (gate g, column jj); wave wv owns 4 batches in registers.
    const int l   = tid & 63;
    const int wv  = tid >> 6;                 // 0..7
    const int g   = l >> 4;
    const int jj  = l & 15;
    const int jg  = j0 + jj;
    const int b0w = bg * BPG + wv * 4;

    const float* wxs = (g == 0) ? wgx : (g == 1) ? wix : (g == 2) ? wfx : wox;
    const float* bss = (g == 0) ? bgp : (g == 1) ? bip : (g == 2) ? bfp : bop;
    const float wx = wxs[jg];
    const float bs = bss[jg];

    // bpermute byte-indices: gate-0..3 lanes holding this jj
    const int ix0 = (jj + 0)  << 2;
    const int ix1 = (jj + 16) << 2;
    const int ix2 = (jj + 32) << 2;
    const int ix3 = (jj + 48) << 2;

    const float4* wr = (const float4*)lds;
    float* hls = lds + WF;                    // h staging region
    // stage geometry: wave wv covers its 4 batches x 64 k = 1024 B, base wv*1 KiB;
    // lane l writes base + l*16 -> layout hls[buf][4*wv + (l>>4)][64k] LINEAR. ok.
    float* stage_base = hls + wv * 256;       // + bsel*HCH at use
    const int bsrc = (b0w + (l >> 4)) * H_ + ((l & 15) << 2);   // float offset in hb

    float c0 = 0.f, c1 = 0.f, c2 = 0.f, c3 = 0.f;

    for (int t = 0; t < T_; ++t) {
        if (t > 0) {
            if (tid == 0) {
                while (__hip_atomic_load(&cnt[t * NGRP + bg], __ATOMIC_RELAXED,
                                         __HIP_MEMORY_SCOPE_AGENT) < NJT) {
                    __builtin_amdgcn_s_sleep(1);
                }
                (void)__hip_atomic_load(&cnt[t * NGRP + bg], __ATOMIC_ACQUIRE,
                                        __HIP_MEMORY_SCOPE_AGENT);
            }
            __syncthreads();
        }

        const float xt0 = x[(b0w + 0) * T_ + t];
        const float xt1 = x[(b0w + 1) * T_ + t];
        const float xt2 = x[(b0w + 2) * T_ + t];
        const float xt3 = x[(b0w + 3) * T_ + t];

        const float* hb = hbuf + (size_t)(t & 1) * B_ * H_;

        float a0 = 0.f, a1 = 0.f, a2 = 0.f, a3 = 0.f;

        // prologue: stage super-chunk 0 (k 0..63) into h buf 0
        stage_h16(hb + bsrc, stage_base);
        __syncthreads();   // drains vmcnt -> buf0 ready

        // 8 super-chunks of 64 k; LDS-only inner loop, DMA prefetch 1 ahead.
        #pragma unroll 1
        for (int sc = 0; sc < 8; ++sc) {
            const int bsel = sc & 1;
            if (sc < 7) {
                // async stage next super-chunk into the other buffer (zero VGPR)
                stage_h16(hb + bsrc + ((sc + 1) << 6), stage_base + (bsel ^ 1) * HCH);
                __builtin_amdgcn_sched_barrier(0);   // pin issue point (no reg cost)
            }
            const float4* hq = (const float4*)(hls + bsel * HCH + wv * 256);
            const int kc0 = sc << 4;
            #pragma unroll
            for (int c = 0; c < 16; ++c) {
                const float4 w4 = wr[((kc0 + c) << 6) + l];
                const float4 h0 = hq[c];          // batch b0w+0, k-quad c (bcast)
                const float4 h1 = hq[16 + c];     // batch b0w+1
                const float4 h2 = hq[32 + c];     // batch b0w+2
                const float4 h3 = hq[48 + c];     // batch b0w+3
                FMA4(a0, h0, w4) FMA4(a1, h1, w4)
                FMA4(a2, h2, w4) FMA4(a3, h3, w4)
            }
            // barrier: (a) next stage vmcnt-drained, (b) all waves done with bsel
            __syncthreads();
        }

        float* hw  = hbuf + (size_t)((t + 1) & 1) * B_ * H_;
        float* hwp = hw + b0w * H_ + jg;

        EPI(0, a0, c0) EPI(1, a1, c1) EPI(2, a2, c2) EPI(3, a3, c3)

        __syncthreads();   // s_waitcnt vmcnt(0) before s_barrier: h stores drained
        if (tid == 0) {
            // RELEASE fetch_add alone provides the store->flag release fence.
            __hip_atomic_fetch_add(&cnt[(t + 1) * NGRP + bg], 1u,
                                   __ATOMIC_RELEASE, __HIP_MEMORY_SCOPE_AGENT);
        }
    }
}

// out[b][c] = dot_seq(h_T[b], wph[c]) + bp[c]  — bit-identical chain to r12's proj
__global__ void __launch_bounds__(64) proj_kernel(
    const float* __restrict__ hbuf, const float* __restrict__ wph,
    const float* __restrict__ bp, float* __restrict__ out)
{
    const int b = blockIdx.x, tid = threadIdx.x;
    const float* h = hbuf + (size_t)b * H_;   // final h in buffer 0 (T even)
    if (tid < C_) {
        float acc = 0.f;
        for (int k = 0; k < H_; ++k)
            acc = __fmaf_rn(h[k], wph[tid * H_ + k], acc);
        out[b * C_ + tid] = __fadd_rn(acc, bp[tid]);
    }
}

extern "C" void kernel_launch(void* const* d_in, const int* in_sizes, int n_in,
                              void* d_out, int out_size, void* d_ws, size_t ws_size,
                              hipStream_t stream)
{
    const float* x   = (const float*)d_in[0];
    const float* wgx = (const float*)d_in[1];
    const float* wgh = (const float*)d_in[2];
    const float* bgp = (const float*)d_in[3];
    const float* wix = (const float*)d_in[4];
    const float* wih = (const float*)d_in[5];
    const float* bip = (const float*)d_in[6];
    const float* wfx = (const float*)d_in[7];
    const float* wfh = (const float*)d_in[8];
    const float* bfp = (const float*)d_in[9];
    const float* wox = (const float*)d_in[10];
    const float* woh = (const float*)d_in[11];
    const float* bop = (const float*)d_in[12];
    const float* wph = (const float*)d_in[13];
    const float* bp  = (const float*)d_in[14];
    float* out = (float*)d_out;

    float* hbuf = (float*)d_ws;                                   // 2*B*H f32 = 1 MB
    unsigned int* cnt = (unsigned int*)((char*)d_ws + (size_t)2 * B_ * H_ * 4);
    size_t zero_bytes = (size_t)2 * B_ * H_ * 4 + (size_t)(T_ + 1) * NGRP * 4;
    hipMemsetAsync(d_ws, 0, zero_bytes, stream);   // h0 = 0, counters = 0

    hipFuncSetAttribute((const void*)lstm_fast,
                        hipFuncAttributeMaxDynamicSharedMemorySize, LDS_BYTES);

    void* args[] = {&x, &wgh, &wih, &wfh, &woh, &wgx, &wix, &wfx, &wox,
                    &bgp, &bip, &bfp, &bop, &hbuf, &cnt};
    hipLaunchCooperativeKernel((const void*)lstm_fast, dim3(NGRP * NJT), dim3(NTHR),
                               args, LDS_BYTES, stream);

    proj_kernel<<<B_, 64, 0, stream>>>(hbuf, wph, bp, out);
}